// Round 10
// baseline (289.386 us; speedup 1.0000x reference)
//
#include <hip/hip_runtime.h>
#include <hip/hip_bf16.h>

#define HIDDEN 1024
#define B_SZ 32
#define S_SZ 2048
#define M_TOT (B_SZ * S_SZ)          // 65536 rows
#define MASKED_BIAS -10000.0f

using bf16   = __bf16;
using bf16x4 = __attribute__((ext_vector_type(4))) __bf16;
using bf16x8 = __attribute__((ext_vector_type(8))) __bf16;
using f32x4  = __attribute__((ext_vector_type(4))) float;

__device__ __forceinline__ float tanh_fast(float x) {
    float xc = fminf(fmaxf(x, -15.f), 15.f);
    float e2 = __expf(2.f * xc);
    return (e2 - 1.f) * __frcp_rn(e2 + 1.f);
}

// ---------------------------------------------------------------------------
// Kernel 0a: W_K f32 -> bf16 (2 MB, L2-resident B operand)
// ---------------------------------------------------------------------------
__global__ __launch_bounds__(256) void k_wconv(
    const float* __restrict__ W, bf16* __restrict__ out)
{
    int i = blockIdx.x * 256 + threadIdx.x;
    const float4* p = (const float4*)W + (size_t)i * 2;
    float4 a = p[0], b = p[1];
    bf16x8 v = { (bf16)a.x, (bf16)a.y, (bf16)a.z, (bf16)a.w,
                 (bf16)b.x, (bf16)b.y, (bf16)b.z, (bf16)b.w };
    *(bf16x8*)(out + (size_t)i * 8) = v;
}

// ---------------------------------------------------------------------------
// Kernel 0b: K f32 -> bf16 (128 MB A operand)
// ---------------------------------------------------------------------------
__global__ __launch_bounds__(256) void k_kconv(
    const float* __restrict__ K, bf16* __restrict__ out)
{
    size_t i = (size_t)blockIdx.x * 256 + threadIdx.x;
    const float4* p = (const float4*)K + i * 2;
    float4 a = p[0], b = p[1];
    bf16x8 v = { (bf16)a.x, (bf16)a.y, (bf16)a.z, (bf16)a.w,
                 (bf16)b.x, (bf16)b.y, (bf16)b.z, (bf16)b.w };
    *(bf16x8*)(out + i * 8) = v;
}

// ---------------------------------------------------------------------------
// Kernel 1: hl_plus[b][g] = dot(h[b,:], W_h[g,:]) + b_h[g] + b_K[g] + b_cov[g]
// ---------------------------------------------------------------------------
__global__ __launch_bounds__(256) void k_hlplus(
    const float* __restrict__ h, const float* __restrict__ W_h,
    const float* __restrict__ b_h, const float* __restrict__ b_K,
    const float* __restrict__ b_cov, float* __restrict__ hl_plus)
{
    int wid  = blockIdx.x * 4 + (threadIdx.x >> 6);
    int lane = threadIdx.x & 63;
    int b = wid & 31;
    int g = wid >> 5;
    const float4* hv = (const float4*)(h + b * HIDDEN);
    const float4* wv = (const float4*)(W_h + g * HIDDEN);
    float acc = 0.f;
#pragma unroll
    for (int i = 0; i < 4; ++i) {
        float4 a = hv[i * 64 + lane];
        float4 w = wv[i * 64 + lane];
        acc += a.x * w.x + a.y * w.y + a.z * w.z + a.w * w.w;
    }
#pragma unroll
    for (int off = 32; off; off >>= 1) acc += __shfl_xor(acc, off);
    if (lane == 0)
        hl_plus[b * HIDDEN + g] = acc + b_h[g] + b_K[g] + b_cov[g];
}

// ===========================================================================
// Kernel 2 (R10): exact m97 concurrency. 128x128 tile, BK=32, 256 threads =
// 4 waves (2M x 2N, wave tile 64x64). LDS 33 KB -> 4 blocks/CU, 16 waves/CU,
// 4-way phase diversity covers each block's barrier vmcnt-drain with other
// blocks' MFMA (m97/m114 mechanism). One __syncthreads per K-tile. All
// staging via global_load_lds from bf16; R7-proven conflict-free XOR swizzle:
// LDS[row][chunk c] = global chunk c ^ ((row>>1)&3).
// ===========================================================================
#define NT_N 8

__global__ __launch_bounds__(256, 4) void k_fusedA(
    const bf16*  __restrict__ Kbf,      // [65536][1024] bf16
    const bf16*  __restrict__ Bbf,      // [1024][1024] bf16 (W_K)
    const float* __restrict__ hl_plus,
    const float* __restrict__ W_cov,
    const float* __restrict__ cov,
    const float* __restrict__ W_v,
    float* __restrict__ e_part)         // [8][65536]
{
    __shared__ __align__(16) bf16 As[2][128][32];   // 16 KB
    __shared__ __align__(16) bf16 Bs[2][128][32];   // 16 KB
    __shared__ float e_buf[128][2];                 // 1 KB

    const int tid = threadIdx.x;
    const int bid = blockIdx.x;
    // XCD-bijective swizzle: 4096 blocks, 512/XCD, nt fastest within XCD.
    const int lid = (bid & 7) * 512 + (bid >> 3);
    const int mt  = lid >> 3;            // 512 m-tiles (128 rows)
    const int nt  = lid & 7;             // 8 n-tiles (128 cols)
    const int row0 = mt * 128;
    const int col0 = nt * 128;

    const int w    = tid >> 6;           // wave 0..3
    const int lane = tid & 63;
    const int wm   = w >> 1;             // M-half (64 rows)
    const int wn   = w & 1;              // N-half (64 cols)
    const int lr   = lane & 15;
    const int kb   = lane >> 4;
    const int colA = (kb ^ ((lr >> 1) & 3)) * 8;   // read-side swizzled col

    // stage geometry: one gload instr per wave = 16 rows x 64B (4x16B chunks);
    // source chunk pre-swizzled: lane l -> chunk (l&3) ^ ((l>>3)&3).
    // 4 waves cover 64 rows per issue; 2 issues each for A(128) and B(128).
    const int srow = lane >> 2;
    const int gch  = (lane & 3) ^ ((lane >> 3) & 3);
    const bf16* Abase = Kbf + (size_t)(row0 + w * 16 + srow) * HIDDEN + gch * 8;
    const bf16* Bbase = Bbf + (size_t)(col0 + w * 16 + srow) * HIDDEN + gch * 8;

    f32x4 acc[4][4] = {};

#define STAGE(KT, BUF)                                                    \
    __builtin_amdgcn_global_load_lds(                                     \
        (const __attribute__((address_space(1))) void*)(Abase + (KT) * 32),\
        (__attribute__((address_space(3))) void*)&As[BUF][w * 16][0],     \
        16, 0, 0);                                                        \
    __builtin_amdgcn_global_load_lds(                                     \
        (const __attribute__((address_space(1))) void*)                   \
            (Abase + (size_t)64 * HIDDEN + (KT) * 32),                    \
        (__attribute__((address_space(3))) void*)&As[BUF][64 + w * 16][0],\
        16, 0, 0);                                                        \
    __builtin_amdgcn_global_load_lds(                                     \
        (const __attribute__((address_space(1))) void*)(Bbase + (KT) * 32),\
        (__attribute__((address_space(3))) void*)&Bs[BUF][w * 16][0],     \
        16, 0, 0);                                                        \
    __builtin_amdgcn_global_load_lds(                                     \
        (const __attribute__((address_space(1))) void*)                   \
            (Bbase + (size_t)64 * HIDDEN + (KT) * 32),                    \
        (__attribute__((address_space(3))) void*)&Bs[BUF][64 + w * 16][0],\
        16, 0, 0);

#define TILE_COMPUTE(BUF)                                                 \
    {                                                                     \
        bf16x8 afr[4], bfr[4];                                            \
        _Pragma("unroll") for (int j = 0; j < 4; ++j)                     \
            afr[j] = *(const bf16x8*)                                     \
                &As[BUF][wm * 64 + j * 16 + lr][colA];                    \
        _Pragma("unroll") for (int n = 0; n < 4; ++n)                     \
            bfr[n] = *(const bf16x8*)&Bs[BUF][wn * 64 + n * 16 + lr][colA];\
        __builtin_amdgcn_s_setprio(1);                                    \
        _Pragma("unroll") for (int j = 0; j < 4; ++j)                     \
            _Pragma("unroll") for (int n = 0; n < 4; ++n)                 \
                acc[j][n] = __builtin_amdgcn_mfma_f32_16x16x32_bf16(      \
                    afr[j], bfr[n], acc[j][n], 0, 0, 0);                  \
        __builtin_amdgcn_s_setprio(0);                                    \
    }

    // prologue: stage tile 0 into buf0 (drained by __syncthreads)
    STAGE(0, 0)
    __syncthreads();

    // tiles 0..29 (stage t+1 each; one barrier per tile)
    for (int i = 0; i < 15; ++i) {
        const int t = i * 2;
        STAGE(t + 1, 1)          // tile t   reads buf0, stages t+1 -> buf1
        TILE_COMPUTE(0)
        __syncthreads();
        STAGE(t + 2, 0)          // tile t+1 reads buf1, stages t+2 -> buf0
        TILE_COMPUTE(1)
        __syncthreads();
    }
    // tile 30: stage 31 -> buf1
    STAGE(31, 1)
    TILE_COMPUTE(0)
    __syncthreads();
    // tile 31: compute only
    TILE_COMPUTE(1)

    // ------------------- epilogue: tanh + dot(W_v) reduction ----------------
    const int bidx = row0 >> 11;          // 128-row tiles never straddle batch
    float hlv[4], wcv[4], wvv[4];
#pragma unroll
    for (int n = 0; n < 4; ++n) {
        int g = col0 + wn * 64 + n * 16 + lr;
        hlv[n] = hl_plus[bidx * HIDDEN + g];
        wcv[n] = W_cov[g];
        wvv[n] = W_v[g];
    }
#pragma unroll
    for (int j = 0; j < 4; ++j) {
#pragma unroll
        for (int i = 0; i < 4; ++i) {
            int rloc = wm * 64 + j * 16 + kb * 4 + i;
            float cv = cov[row0 + rloc];
            float ep = 0.f;
#pragma unroll
            for (int n = 0; n < 4; ++n) {
                float arg = acc[j][n][i] + hlv[n] + cv * wcv[n];
                ep += tanh_fast(arg) * wvv[n];
            }
            ep += __shfl_xor(ep, 1);
            ep += __shfl_xor(ep, 2);
            ep += __shfl_xor(ep, 4);
            ep += __shfl_xor(ep, 8);
            if (lr == 0) e_buf[rloc][wn] = ep;
        }
    }
    __syncthreads();
    if (tid < 128)
        e_part[(size_t)nt * M_TOT + row0 + tid] = e_buf[tid][0] + e_buf[tid][1];

#undef STAGE
#undef TILE_COMPUTE
}

// ---------------------------------------------------------------------------
// Kernel 3: per-batch softmax over S=2048; also emits cov_new = cov + a
// ---------------------------------------------------------------------------
__global__ __launch_bounds__(256) void k_softmax(
    const float* __restrict__ e_part, const float* __restrict__ mask,
    const float* __restrict__ cov, const float* __restrict__ b_v,
    float* __restrict__ a_out, float* __restrict__ cov_out)
{
    __shared__ float red[8];
    int b = blockIdx.x, tid = threadIdx.x;
    float bv = b_v[0];
    float ev[8];
    float mx = -1e30f;
#pragma unroll
    for (int j = 0; j < 8; ++j) {
        int s = j * 256 + tid;
        int idx = b * S_SZ + s;
        float e = bv;
#pragma unroll
        for (int p = 0; p < 8; ++p) e += e_part[(size_t)p * M_TOT + idx];
        e += mask[idx] * MASKED_BIAS;
        ev[j] = e;
        mx = fmaxf(mx, e);
    }
#pragma unroll
    for (int off = 32; off; off >>= 1) mx = fmaxf(mx, __shfl_xor(mx, off));
    if ((tid & 63) == 0) red[tid >> 6] = mx;
    __syncthreads();
    mx = fmaxf(fmaxf(red[0], red[1]), fmaxf(red[2], red[3]));
    float sum = 0.f;
#pragma unroll
    for (int j = 0; j < 8; ++j) { ev[j] = __expf(ev[j] - mx); sum += ev[j]; }
#pragma unroll
    for (int off = 32; off; off >>= 1) sum += __shfl_xor(sum, off);
    if ((tid & 63) == 0) red[4 + (tid >> 6)] = sum;
    __syncthreads();
    sum = red[4] + red[5] + red[6] + red[7];
    float inv = 1.f / sum;
#pragma unroll
    for (int j = 0; j < 8; ++j) {
        int idx = b * S_SZ + j * 256 + tid;
        float a = ev[j] * inv;
        a_out[idx]   = a;
        cov_out[idx] = cov[idx] + a;
    }
}

// ---------------------------------------------------------------------------
// Kernel 4: context partials from bf16 K (L3-warm after GEMM), 16 s-chunks
// ---------------------------------------------------------------------------
__global__ __launch_bounds__(256) void k_ctx_part_bf(
    const bf16* __restrict__ Kbf, const float* __restrict__ a_out,
    float* __restrict__ part_out)
{
    int sc = blockIdx.x;   // 0..15
    int b  = blockIdx.y;   // 0..31
    int tid = threadIdx.x;
    const bf16* Kb = Kbf + ((size_t)b * S_SZ + sc * 128) * HIDDEN;
    const float* ab = a_out + b * S_SZ + sc * 128;
    float4 acc = {0.f, 0.f, 0.f, 0.f};
#pragma unroll 4
    for (int s = 0; s < 128; ++s) {
        float av = ab[s];
        bf16x4 kv = *(const bf16x4*)(Kb + (size_t)s * HIDDEN + tid * 4);
        acc.x += av * (float)kv[0];
        acc.y += av * (float)kv[1];
        acc.z += av * (float)kv[2];
        acc.w += av * (float)kv[3];
    }
    ((float4*)part_out)[((size_t)b * 16 + sc) * 256 + tid] = acc;
}

// ---------------------------------------------------------------------------
// Kernel 5: out[b][h] = sum_sc part_out[b][sc][h]
// ---------------------------------------------------------------------------
__global__ __launch_bounds__(256) void k_ctx_reduce(
    const float* __restrict__ part_out, float* __restrict__ out, int nc)
{
    int b = blockIdx.x, tid = threadIdx.x;
    float4 acc = {0.f, 0.f, 0.f, 0.f};
    for (int sc = 0; sc < nc; ++sc) {
        float4 v = ((const float4*)part_out)[((size_t)b * nc + sc) * 256 + tid];
        acc.x += v.x; acc.y += v.y; acc.z += v.z; acc.w += v.w;
    }
    ((float4*)out)[b * 256 + tid] = acc;
}

// ---------------------------------------------------------------------------
extern "C" void kernel_launch(void* const* d_in, const int* in_sizes, int n_in,
                              void* d_out, int out_size, void* d_ws, size_t ws_size,
                              hipStream_t stream)
{
    const float* h     = (const float*)d_in[0];
    const float* Kin   = (const float*)d_in[1];
    const float* cov   = (const float*)d_in[2];
    const float* mask  = (const float*)d_in[3];
    const float* W_h   = (const float*)d_in[4];
    const float* b_h   = (const float*)d_in[5];
    const float* W_K   = (const float*)d_in[6];
    const float* b_K   = (const float*)d_in[7];
    const float* W_cov = (const float*)d_in[8];
    const float* b_cov = (const float*)d_in[9];
    const float* W_v   = (const float*)d_in[10];
    const float* b_v   = (const float*)d_in[11];

    float* out_ctx = (float*)d_out;            // 32*1024
    float* a_out   = out_ctx + B_SZ * HIDDEN;  // 32*2048
    float* cov_out = a_out + M_TOT;            // 32*2048

    float* ws       = (float*)d_ws;
    float* hl_plus  = ws;                        // 32768 f32
    float* e_part   = ws + 32768;                // 8*65536 f32 = 2 MB
    float* part_out = e_part;                    // alias (sequential use, 2 MB)
    bf16*  Bbf      = (bf16*)(e_part + 8 * M_TOT);          // 2 MB
    bf16*  Kbf      = (bf16*)((char*)Bbf + (size_t)HIDDEN * HIDDEN * sizeof(bf16));

    k_wconv<<<512, 256, 0, stream>>>(W_K, Bbf);
    k_hlplus<<<8192, 256, 0, stream>>>(h, W_h, b_h, b_K, b_cov, hl_plus);
    k_kconv<<<(M_TOT * HIDDEN / 8) / 256, 256, 0, stream>>>(Kin, Kbf);
    k_fusedA<<<512 * NT_N, 256, 0, stream>>>(
        Kbf, Bbf, hl_plus, W_cov, cov, W_v, e_part);
    k_softmax<<<B_SZ, 256, 0, stream>>>(e_part, mask, cov, b_v, a_out, cov_out);
    dim3 g4(16, B_SZ);
    k_ctx_part_bf<<<g4, 256, 0, stream>>>(Kbf, a_out, part_out);
    k_ctx_reduce<<<B_SZ, 256, 0, stream>>>(part_out, out_ctx, 16);
}